// Round 1
// baseline (315.444 us; speedup 1.0000x reference)
//
#include <hip/hip_runtime.h>
#include <math.h>

// ---------------- constants ----------------
// LMAX=3, NMAX=3, RC=6, UNIT=RC/6=1.0, NSPEC=4, L=4
// c[s][n][a][b]: 4*4*4*4 = 256 floats; comp k = n*16 + a*4 + b  (64 comps)
constexpr int   NSPEC    = 4;
constexpr float RC       = 6.0f;
constexpr int   REPL     = 16;               // LDS accumulator replicas
constexpr int   S_STRIDE = 65;               // 64 comps + 1 pad
constexpr int   R_STRIDE = 4 * S_STRIDE + 1; // 261 (odd -> bank swizzle)
constexpr int   LDS_FLOATS = REPL * R_STRIDE;

__device__ inline void global_fadd(float* p, float v) {
    // gfx950 has HW global_atomic_add_f32; unsafeAtomicAdd forces it.
    unsafeAtomicAdd(p, v);
}

// ---------------- kernel 0: zero the 256-float global accumulator ----------
__global__ __launch_bounds__(256) void soap_zero(float* __restrict__ c) {
    c[threadIdx.x] = 0.0f;
}

// ---------------- kernel 1: per-atom features + segmented accumulation -----
__global__ __launch_bounds__(256) void soap_accum(const float* __restrict__ coo,
                                                  const int*   __restrict__ numbers,
                                                  float*       __restrict__ c_glob,
                                                  int n) {
    __shared__ float sh[LDS_FLOATS];
    for (int i = threadIdx.x; i < LDS_FLOATS; i += 256) sh[i] = 0.0f;
    __syncthreads();

    const int repl = threadIdx.x & (REPL - 1);
    const int tid    = blockIdx.x * 256 + threadIdx.x;
    const int stride = gridDim.x * 256;

    for (int i = tid; i < n; i += stride) {
        const float x = coo[3 * i + 0];
        const float y = coo[3 * i + 1];
        const float z = coo[3 * i + 2];
        const int   s = numbers[i];
        const float r2 = x * x + y * y + z * z;
        const float d  = sqrtf(r2);
        if (d < RC) {
            const float t = 1.0f - d * (1.0f / RC);
            const float r = __expf(-0.5f * r2) * t * t;   // radial * cutoff

            // ---- regular solid harmonics, (4,4) grid, unrolled ----
            float Y[16];
            Y[0 * 4 + 0] = 1.0f;                       // Re00
            const float Re11 = 0.5f * x, Im11 = 0.5f * y, Re10 = z;
            Y[1 * 4 + 1] = Re10;                       // Re10
            Y[1 * 4 + 0] = Re11;                       // Re11
            Y[0 * 4 + 1] = Im11;                       // Im11
            const float Re22 = 0.25f * (x * Re11 - y * Im11);
            const float Im22 = 0.25f * (x * Im11 + y * Re11);
            const float Re21 = z * Re11, Im21 = z * Im11;
            const float Re20 = 0.25f * (3.0f * z * Re10 - r2);
            Y[2 * 4 + 2] = Re20;
            Y[2 * 4 + 1] = Re21;
            Y[1 * 4 + 2] = Im21;
            Y[2 * 4 + 0] = Re22;
            Y[0 * 4 + 2] = Im22;
            const float Re33 = (x * Re22 - y * Im22) * (1.0f / 6.0f);
            const float Im33 = (x * Im22 + y * Re22) * (1.0f / 6.0f);
            const float Re32 = z * Re22, Im32 = z * Im22;
            const float Re30 = (5.0f * z * Re20 - r2 * Re10) * (1.0f / 9.0f);
            const float Re31 = (5.0f * z * Re21 - r2 * Re11) * (1.0f / 8.0f);
            const float Im31 = (5.0f * z * Im21 - r2 * Im11) * (1.0f / 8.0f);
            Y[3 * 4 + 3] = Re30;
            Y[3 * 4 + 2] = Re31;
            Y[2 * 4 + 3] = Im31;
            Y[3 * 4 + 1] = Re32;
            Y[1 * 4 + 3] = Im32;
            Y[3 * 4 + 0] = Re33;
            Y[0 * 4 + 3] = Im33;

            const float f0 = r;
            const float f1 = f0 * r2;
            const float f2 = f1 * r2;
            const float f3 = f2 * r2;

            const int base = repl * R_STRIDE + s * S_STRIDE;
            #pragma unroll
            for (int q = 0; q < 16; ++q) {
                atomicAdd(&sh[base +  0 + q], f0 * Y[q]);  // ds_add_f32, no return
                atomicAdd(&sh[base + 16 + q], f1 * Y[q]);
                atomicAdd(&sh[base + 32 + q], f2 * Y[q]);
                atomicAdd(&sh[base + 48 + q], f3 * Y[q]);
            }
        }
    }
    __syncthreads();

    // reduce the 16 replicas; thread t owns comp (s,k) = (t>>6, t&63)
    const int t = threadIdx.x;
    const int s = t >> 6, k = t & 63;
    float sum = 0.0f;
    #pragma unroll
    for (int rr = 0; rr < REPL; ++rr) sum += sh[rr * R_STRIDE + s * S_STRIDE + k];
    global_fadd(&c_glob[t], sum);
}

// ---------------- kernel 2: bilinear contraction + normalize ---------------
__global__ __launch_bounds__(1024) void soap_finish(const float* __restrict__ c_glob,
                                                    float* __restrict__ out) {
    __shared__ float c[256];
    __shared__ float red[16];
    __shared__ float snorm;
    const int t = threadIdx.x;
    if (t < 256) c[t] = c_glob[t];
    __syncthreads();

    // p index (i,j,k,n,x), t = i*256 + j*64 + k*16 + n*4 + x
    const int x  = t & 3;
    const int nn = (t >> 2) & 3;
    const int kk = (t >> 4) & 3;
    const int j  = (t >> 6) & 3;
    const int i  = (t >> 8) & 3;

    // nnp[i,j,k,n,a,b] = c[j,n,a,b] * c[i,k,a,b]
    // p1 = sum_b nnp[..,x,b]*Yr[x,b];  p2 = sum_a nnp[..,a,x]*Yi[a,x]
    float p1 = 0.0f, p2 = 0.0f;
    #pragma unroll
    for (int b = 0; b < 4; ++b) {
        const float yr = (x > b) ? 2.0f : ((x == b) ? 1.0f : 0.0f);
        p1 += yr * c[((j * 4 + nn) * 4 + x) * 4 + b] * c[((i * 4 + kk) * 4 + x) * 4 + b];
    }
    #pragma unroll
    for (int a = 0; a < 4; ++a) {
        const float yi = (x > a) ? 2.0f : 0.0f;
        p2 += yi * c[((j * 4 + nn) * 4 + a) * 4 + x] * c[((i * 4 + kk) * 4 + a) * 4 + x];
    }

    // nnl[k][n][x] = sqrt(a[k][x] * a[n][x]),  a[n][l] = 1/((2l+1) 2^(2n+l) n! (n+l)!)
    const double fact[8] = {1, 1, 2, 6, 24, 120, 720, 5040};
    const double ak = 1.0 / ((2 * x + 1) * exp2((double)(2 * kk + x)) * fact[kk] * fact[kk + x]);
    const double an = 1.0 / ((2 * x + 1) * exp2((double)(2 * nn + x)) * fact[nn] * fact[nn + x]);
    const float val = (p1 + p2) * (float)sqrt(ak * an);

    // global L2 norm over all 1024 values
    float sq = val * val;
    #pragma unroll
    for (int off = 32; off > 0; off >>= 1) sq += __shfl_down(sq, off, 64);
    if ((t & 63) == 0) red[t >> 6] = sq;
    __syncthreads();
    if (t == 0) {
        float ssum = 0.0f;
        #pragma unroll
        for (int w = 0; w < 16; ++w) ssum += red[w];
        snorm = sqrtf(ssum);
    }
    __syncthreads();

    out[t] = val / (snorm + 1.1920929e-07f);
}

// ---------------- launch ----------------
extern "C" void kernel_launch(void* const* d_in, const int* in_sizes, int n_in,
                              void* d_out, int out_size, void* d_ws, size_t ws_size,
                              hipStream_t stream) {
    const float* coo     = (const float*)d_in[0];
    const int*   numbers = (const int*)d_in[1];
    const int    n       = in_sizes[1];          // atom count (in_sizes[0] = 3n)
    float*       c_glob  = (float*)d_ws;         // 256-float global accumulator
    float*       out     = (float*)d_out;        // 1024 floats

    soap_zero  <<<1,   256, 0, stream>>>(c_glob);
    soap_accum <<<512, 256, 0, stream>>>(coo, numbers, c_glob, n);
    soap_finish<<<1,  1024, 0, stream>>>(c_glob, out);
}

// Round 4
// 100.367 us; speedup vs baseline: 3.1429x; 3.1429x over previous
//
#include <hip/hip_runtime.h>
#include <math.h>

// LMAX=3, NMAX=3, RC=6, UNIT=1.0, NSPEC=4, L=4
// c[s][n][a][b]: 256 floats; per-species comp k = n*16 + a*4 + b (64 comps)
constexpr int   NB    = 256;          // accum blocks (1 per CU)
constexpr int   BT    = 512;          // threads per block (8 waves)
constexpr int   WAVES = BT / 64;      // 8 waves: species = wid & 3 (2 cohorts/species/block)
constexpr int   COHORTS = NB * WAVES / 4;   // 512 cohorts per species
constexpr float RC    = 6.0f;

// ---------------- kernel 1: per-atom features, register accumulation -------
__global__ __launch_bounds__(BT) void soap_accum(const float* __restrict__ coo,
                                                 const int*   __restrict__ numbers,
                                                 float*       __restrict__ partials,
                                                 int n) {
    const int lane = threadIdx.x & 63;
    const int wid  = threadIdx.x >> 6;
    const int ws   = wid & 3;                              // this wave's species
    const int cohort = blockIdx.x * (WAVES / 4) + (wid >> 2);
    const int stride = COHORTS * 64;

    float acc[64];
    #pragma unroll
    for (int k = 0; k < 64; ++k) acc[k] = 0.0f;

    int i = cohort * 64 + lane;
    // prime the software pipeline
    int   j0 = (i < n) ? i : 0;
    float x = coo[3 * j0 + 0];
    float y = coo[3 * j0 + 1];
    float z = coo[3 * j0 + 2];
    int   s = numbers[j0];

    for (; i < n; ) {
        const int inext = i + stride;
        const int jn = (inext < n) ? inext : (n - 1);      // clamped prefetch
        const float xn = coo[3 * jn + 0];
        const float yn = coo[3 * jn + 1];
        const float zn = coo[3 * jn + 2];
        const int   sn = numbers[jn];

        const float r2 = x * x + y * y + z * z;
        const float d  = sqrtf(r2);
        float t = 1.0f - d * (1.0f / RC);
        t = fmaxf(t, 0.0f);                                // cutoff -> 0 outside RC
        float r = __expf(-0.5f * r2) * t * t;
        r = (s == ws) ? r : 0.0f;                          // species mask, branchless

        // ---- regular solid harmonics on the (4,4) grid ----
        float Y[16];
        Y[0]  = 1.0f;                                      // (0,0) Re00
        const float Re11 = 0.5f * x, Im11 = 0.5f * y, Re10 = z;
        Y[5]  = Re10;                                      // (1,1)
        Y[4]  = Re11;                                      // (1,0)
        Y[1]  = Im11;                                      // (0,1)
        const float Re22 = 0.25f * (x * Re11 - y * Im11);
        const float Im22 = 0.25f * (x * Im11 + y * Re11);
        const float Re21 = z * Re11, Im21 = z * Im11;
        const float Re20 = 0.25f * (3.0f * z * Re10 - r2);
        Y[10] = Re20;                                      // (2,2)
        Y[9]  = Re21;                                      // (2,1)
        Y[6]  = Im21;                                      // (1,2)
        Y[8]  = Re22;                                      // (2,0)
        Y[2]  = Im22;                                      // (0,2)
        const float Re33 = (x * Re22 - y * Im22) * (1.0f / 6.0f);
        const float Im33 = (x * Im22 + y * Re22) * (1.0f / 6.0f);
        const float Re32 = z * Re22, Im32 = z * Im22;
        const float Re30 = (5.0f * z * Re20 - r2 * Re10) * (1.0f / 9.0f);
        const float Re31 = (5.0f * z * Re21 - r2 * Re11) * (1.0f / 8.0f);
        const float Im31 = (5.0f * z * Im21 - r2 * Im11) * (1.0f / 8.0f);
        Y[15] = Re30;                                      // (3,3)
        Y[14] = Re31;                                      // (3,2)
        Y[11] = Im31;                                      // (2,3)
        Y[13] = Re32;                                      // (3,1)
        Y[7]  = Im32;                                      // (1,3)
        Y[12] = Re33;                                      // (3,0)
        Y[3]  = Im33;                                      // (0,3)

        const float f0 = r;
        const float f1 = f0 * r2;
        const float f2 = f1 * r2;
        const float f3 = f2 * r2;

        #pragma unroll
        for (int q = 0; q < 16; ++q) {
            acc[ 0 + q] += f0 * Y[q];
            acc[16 + q] += f1 * Y[q];
            acc[32 + q] += f2 * Y[q];
            acc[48 + q] += f3 * Y[q];
        }

        x = xn; y = yn; z = zn; s = sn;
        i = inext;
    }

    // ---- block reduction: LDS transpose, no atomics (once per kernel) ----
    __shared__ float sh[64][65];        // one wave's 64 lanes x 64 comps, padded
    __shared__ float sh2[8][64];
    __shared__ float blockpart[256];    // [species][comp]

    for (int w = 0; w < WAVES; ++w) {
        __syncthreads();
        if (wid == w) {
            #pragma unroll
            for (int k = 0; k < 64; ++k) sh[lane][k] = acc[k];
        }
        __syncthreads();
        float p = 0.0f;
        #pragma unroll
        for (int rr = 0; rr < 8; ++rr) p += sh[wid * 8 + rr][lane];
        sh2[wid][lane] = p;
        __syncthreads();
        if (threadIdx.x < 64) {
            float q = 0.0f;
            #pragma unroll
            for (int g = 0; g < 8; ++g) q += sh2[g][threadIdx.x];
            const int sw = w & 3;
            if (w < 4) blockpart[sw * 64 + threadIdx.x] = q;
            else       blockpart[sw * 64 + threadIdx.x] += q;
        }
    }
    __syncthreads();
    if (threadIdx.x < 256)
        partials[blockIdx.x * 256 + threadIdx.x] = blockpart[threadIdx.x];
}

// ---------------- kernel 2: reduce partials + bilinear contraction + norm --
__global__ __launch_bounds__(1024) void soap_finish(const float* __restrict__ partials,
                                                    float* __restrict__ out) {
    __shared__ float c[256];
    __shared__ float cpart[4][256];
    __shared__ float red[16];
    __shared__ float snorm;
    const int t = threadIdx.x;

    // reduce NB block-partials -> c[256]
    {
        const int comp  = t & 255;
        const int chunk = t >> 8;          // 0..3
        float s = 0.0f;
        for (int b = chunk; b < NB; b += 4) s += partials[b * 256 + comp];
        cpart[chunk][comp] = s;
    }
    __syncthreads();
    if (t < 256) c[t] = cpart[0][t] + cpart[1][t] + cpart[2][t] + cpart[3][t];
    __syncthreads();

    // p index (i,j,k,n,x), t = i*256 + j*64 + k*16 + n*4 + x
    const int x  = t & 3;
    const int nn = (t >> 2) & 3;
    const int kk = (t >> 4) & 3;
    const int j  = (t >> 6) & 3;
    const int i  = (t >> 8) & 3;

    float p1 = 0.0f, p2 = 0.0f;
    #pragma unroll
    for (int b = 0; b < 4; ++b) {
        const float yr = (x > b) ? 2.0f : ((x == b) ? 1.0f : 0.0f);
        p1 += yr * c[((j * 4 + nn) * 4 + x) * 4 + b] * c[((i * 4 + kk) * 4 + x) * 4 + b];
    }
    #pragma unroll
    for (int a = 0; a < 4; ++a) {
        const float yi = (x > a) ? 2.0f : 0.0f;
        p2 += yi * c[((j * 4 + nn) * 4 + a) * 4 + x] * c[((i * 4 + kk) * 4 + a) * 4 + x];
    }

    const double fact[8] = {1, 1, 2, 6, 24, 120, 720, 5040};
    const double ak = 1.0 / ((2 * x + 1) * exp2((double)(2 * kk + x)) * fact[kk] * fact[kk + x]);
    const double an = 1.0 / ((2 * x + 1) * exp2((double)(2 * nn + x)) * fact[nn] * fact[nn + x]);
    const float val = (p1 + p2) * (float)sqrt(ak * an);

    float sq = val * val;
    #pragma unroll
    for (int off = 32; off > 0; off >>= 1) sq += __shfl_down(sq, off, 64);
    if ((t & 63) == 0) red[t >> 6] = sq;
    __syncthreads();
    if (t == 0) {
        float ssum = 0.0f;
        #pragma unroll
        for (int w = 0; w < 16; ++w) ssum += red[w];
        snorm = sqrtf(ssum);
    }
    __syncthreads();

    out[t] = val / (snorm + 1.1920929e-07f);
}

// ---------------- launch ----------------
extern "C" void kernel_launch(void* const* d_in, const int* in_sizes, int n_in,
                              void* d_out, int out_size, void* d_ws, size_t ws_size,
                              hipStream_t stream) {
    const float* coo     = (const float*)d_in[0];
    const int*   numbers = (const int*)d_in[1];
    const int    n       = in_sizes[1];
    float*       part    = (float*)d_ws;     // NB*256 floats = 256 KB
    float*       out     = (float*)d_out;

    soap_accum <<<NB, BT, 0, stream>>>(coo, numbers, part, n);
    soap_finish<<<1, 1024, 0, stream>>>(part, out);
}